// Round 1
// baseline (1421.320 us; speedup 1.0000x reference)
//
#include <hip/hip_runtime.h>
#include <stdint.h>

// WindowAttention (Swin, 7x7, C=384, H=12, hd=32, B_=4096, nW=64), fp32 in/out.
// Strategy: bf16 MFMA for all three matmul stages (threshold 3.3e-2 allows it).
//   prep      : cast x / qkv_w / proj_w to bf16, expand rpb table to [12][49][49]
//   gemm_nt<0>: qkv = x @ qkv_w^T + b  (q-part scaled), bf16 out  [200704 x 1152]
//   attn      : per-window flash-style attention (padded 49->64), bf16 out
//   gemm_nt<1>: out = attnout @ proj_w^T + b, fp32 out
// M=200704=1568*128, N=1152=9*128 / 384=3*128, K=384=12*32 -> no edge handling.

typedef unsigned short u16;
typedef short short8 __attribute__((ext_vector_type(8)));   // 8 x bf16 (4 VGPRs)
typedef float f32x4 __attribute__((ext_vector_type(4)));

static __device__ __forceinline__ u16 f2bf(float f) {
  // round-to-nearest-even f32 -> bf16 (inputs are normal; NaN not expected)
  unsigned u = __builtin_bit_cast(unsigned, f);
  return (u16)((u + 0x7fffu + ((u >> 16) & 1u)) >> 16);
}

// async global->LDS, 16B per lane. LDS dest = wave-uniform base + lane*16.
static __device__ __forceinline__ void async_cp16(const u16* g, u16* l) {
  __builtin_amdgcn_global_load_lds(
      (__attribute__((address_space(1))) unsigned int*)g,
      (__attribute__((address_space(3))) unsigned int*)l, 16, 0, 0);
}

// ---------------------------------------------------------------- prep ------
// blocks [0,1024): x -> bf16 (19,267,584 float4)
// blocks [1024,1088): qkv_w (110,592 float4) + proj_w (36,864 float4) -> bf16
// blocks [1088,1096): rpb_full[h][i][j] = rpb_table[rel(i,j)*12 + h]
__global__ __launch_bounds__(256) void prep_kernel(
    const float* __restrict__ x, const float* __restrict__ wq,
    const float* __restrict__ wp, const float* __restrict__ rpt,
    u16* __restrict__ xb, u16* __restrict__ wqb, u16* __restrict__ wpb,
    float* __restrict__ rpbf)
{
  const int bid = blockIdx.x, tid = threadIdx.x;
  if (bid < 1024) {
    const float4* x4 = (const float4*)x;
    ushort4* o4 = (ushort4*)xb;
    for (unsigned i = bid * 256u + tid; i < 19267584u; i += 262144u) {
      float4 v = x4[i];
      ushort4 o; o.x = f2bf(v.x); o.y = f2bf(v.y); o.z = f2bf(v.z); o.w = f2bf(v.w);
      o4[i] = o;
    }
  } else if (bid < 1088) {
    for (unsigned i = (bid - 1024) * 256u + tid; i < 147456u; i += 16384u) {
      if (i < 110592u) {
        float4 v = ((const float4*)wq)[i];
        ushort4 o; o.x = f2bf(v.x); o.y = f2bf(v.y); o.z = f2bf(v.z); o.w = f2bf(v.w);
        ((ushort4*)wqb)[i] = o;
      } else {
        unsigned k = i - 110592u;
        float4 v = ((const float4*)wp)[k];
        ushort4 o; o.x = f2bf(v.x); o.y = f2bf(v.y); o.z = f2bf(v.z); o.w = f2bf(v.w);
        ((ushort4*)wpb)[k] = o;
      }
    }
  } else {
    for (int e = (bid - 1088) * 256 + tid; e < 28812; e += 2048) {
      int h = e / 2401, r2 = e - h * 2401;
      int i = r2 / 49, j = r2 - (r2 / 49) * 49;
      int rel = (i / 7 - j / 7 + 6) * 13 + (i % 7 - j % 7 + 6);
      rpbf[e] = rpt[rel * 12 + h];
    }
  }
}

// ------------------------------------------------------------- NT GEMM ------
// C[m][n] = sum_k A[m][k] * Bw[n][k] (+bias). 128x128 tile, BK=32, 4 waves,
// each wave 64x64 via 4x4 mfma_f32_16x16x32_bf16. m97-pattern staging.
// MODE 0: bf16 out, cols<384 (q) scaled by hd^-0.5.  MODE 1: fp32 out.
template <int MODE>
__global__ __launch_bounds__(256) void gemm_nt(
    const u16* __restrict__ A, const u16* __restrict__ Bw,
    const float* __restrict__ bias, void* __restrict__ Cp, int Ntot)
{
  __shared__ u16 As[128 * 32];   // row-major [row][k], NO padding (global_load_lds)
  __shared__ u16 Bs[128 * 32];
  const int tid = threadIdx.x;
  const int wave = tid >> 6, lane = tid & 63;
  const int lr = lane & 15, quad = lane >> 4;
  const int m0 = blockIdx.y * 128, n0 = blockIdx.x * 128;
  const int wm = (wave & 1) * 64, wn = (wave >> 1) * 64;

  const int e0 = tid * 8;             // staging: thread covers 8 contiguous bf16
  const int row0 = e0 >> 5, col0 = e0 & 31;   // 256 thr * 8 = 2048 elems = 64 rows

  f32x4 acc[4][4] = {};
  for (int k0 = 0; k0 < 384; k0 += 32) {
    __syncthreads();                  // prior iter's frag reads done before overwrite
    async_cp16(&A[(size_t)(m0 + row0) * 384 + k0 + col0],      As + wave * 512);
    async_cp16(&A[(size_t)(m0 + 64 + row0) * 384 + k0 + col0], As + 2048 + wave * 512);
    async_cp16(&Bw[(size_t)(n0 + row0) * 384 + k0 + col0],      Bs + wave * 512);
    async_cp16(&Bw[(size_t)(n0 + 64 + row0) * 384 + k0 + col0], Bs + 2048 + wave * 512);
    __syncthreads();                  // vmcnt(0) drain before barrier (compiler)

    short8 af[4], bf[4];
#pragma unroll
    for (int mi = 0; mi < 4; ++mi)
      af[mi] = *(const short8*)&As[(wm + mi * 16 + lr) * 32 + quad * 8];
#pragma unroll
    for (int ni = 0; ni < 4; ++ni)
      bf[ni] = *(const short8*)&Bs[(wn + ni * 16 + lr) * 32 + quad * 8];
#pragma unroll
    for (int mi = 0; mi < 4; ++mi)
#pragma unroll
      for (int ni = 0; ni < 4; ++ni)
        acc[mi][ni] = __builtin_amdgcn_mfma_f32_16x16x32_bf16(af[mi], bf[ni], acc[mi][ni], 0, 0, 0);
  }

  // epilogue: D[row = wm+mi*16+quad*4+r][col = wn+ni*16+lr]  (m89-verified layout)
  float bv[4];
#pragma unroll
  for (int ni = 0; ni < 4; ++ni) bv[ni] = bias[n0 + wn + ni * 16 + lr];
#pragma unroll
  for (int mi = 0; mi < 4; ++mi)
#pragma unroll
    for (int ni = 0; ni < 4; ++ni) {
      const int gcol = n0 + wn + ni * 16 + lr;
#pragma unroll
      for (int r = 0; r < 4; ++r) {
        const size_t grow = (size_t)(m0 + wm + mi * 16 + quad * 4 + r);
        float v = acc[mi][ni][r] + bv[ni];
        if (MODE == 0) {
          if (gcol < 384) v *= 0.17677669529663687f;   // hd^-0.5, applied to q
          ((u16*)Cp)[grow * Ntot + gcol] = f2bf(v);
        } else {
          ((float*)Cp)[grow * Ntot + gcol] = v;
        }
      }
    }
}

// ------------------------------------------------------------ attention -----
// One block per window; wave w handles heads w, w+4, w+8. Tokens padded 49->64.
// QK^T: both operands loaded straight from global in fragment layout (K=hd=32,
// contiguous 16B in d). S += rpb + mask in C-layout; softmax is quad-local
// (row = quad*4+r lives in 16 lanes of one quad). P -> LDS (bf16, stride 72)
// to convert C-layout -> A-layout; V staged transposed (VT[d][tok]) for the
// B-operand. O normalized by 1/l at the end.
__global__ __launch_bounds__(256) void attn_kernel(
    const u16* __restrict__ qkv, const float* __restrict__ mask,
    const float* __restrict__ rpbf, u16* __restrict__ attnout)
{
  __shared__ float mask_s[2401];        // 9.6 KB, shared by all heads
  __shared__ u16 P_lds[4][64 * 72];     // per-wave, 9.2 KB each
  __shared__ u16 VT[4][32 * 72];        // per-wave V^T, 4.6 KB each
  const int b = blockIdx.x, tid = threadIdx.x;
  const int wave = tid >> 6, lane = tid & 63;
  const int lr = lane & 15, quad = lane >> 4;

  const float* mw = &mask[(size_t)(b & 63) * 2401];   // window-in-group = b % nW
  for (int i = tid; i < 2401; i += 256) mask_s[i] = mw[i];
  __syncthreads();

  const size_t base = (size_t)b * 49 * 1152;
  const short8 z8 = {0, 0, 0, 0, 0, 0, 0, 0};

  for (int h = wave; h < 12; h += 4) {
    // ---- stage V^T: VT[d][tok], pad tokens zeroed (P pad cols are 0 anyway,
    // but keep LDS garbage out of the MFMA) ----
    for (int it = 0; it < 32; ++it) {
      const int idx = it * 64 + lane;
      const int tok = idx >> 5, d = idx & 31;
      u16 v = 0;
      if (tok < 49) v = qkv[base + (size_t)tok * 1152 + 768 + h * 32 + d];
      VT[wave][d * 72 + tok] = v;
    }

    // ---- QK^T ----  A: Q[m=mi*16+lr][k=quad*8+j]   B: K[n=ni*16+lr][k=quad*8+j]
    short8 qf[4], kf[4];
#pragma unroll
    for (int mi = 0; mi < 4; ++mi) {
      const int row = mi * 16 + lr;
      qf[mi] = (row < 49)
          ? *(const short8*)&qkv[base + (size_t)row * 1152 + h * 32 + quad * 8] : z8;
    }
#pragma unroll
    for (int ni = 0; ni < 4; ++ni) {
      const int tok = ni * 16 + lr;
      kf[ni] = (tok < 49)
          ? *(const short8*)&qkv[base + (size_t)tok * 1152 + 384 + h * 32 + quad * 8] : z8;
    }
    f32x4 s[4][4] = {};
#pragma unroll
    for (int mi = 0; mi < 4; ++mi)
#pragma unroll
      for (int ni = 0; ni < 4; ++ni)
        s[mi][ni] = __builtin_amdgcn_mfma_f32_16x16x32_bf16(qf[mi], kf[ni], s[mi][ni], 0, 0, 0);

    // ---- bias + mask + online-softmax (quad-local rows), P -> LDS bf16 ----
    const float* rh = &rpbf[h * 2401];
    float linv[4][4];
#pragma unroll
    for (int mi = 0; mi < 4; ++mi) {
#pragma unroll
      for (int r = 0; r < 4; ++r) {
        const int row = mi * 16 + quad * 4 + r;
        float vals[4];
#pragma unroll
        for (int ni = 0; ni < 4; ++ni) {
          const int col = ni * 16 + lr;
          float v = s[mi][ni][r];
          if (row < 49 && col < 49) v += rh[row * 49 + col] + mask_s[row * 49 + col];
          else v = -1e30f;            // finite neg: pad rows give exp(0)=1, unused
          vals[ni] = v;
        }
        float m = fmaxf(fmaxf(vals[0], vals[1]), fmaxf(vals[2], vals[3]));
        m = fmaxf(m, __shfl_xor(m, 1));
        m = fmaxf(m, __shfl_xor(m, 2));
        m = fmaxf(m, __shfl_xor(m, 4));
        m = fmaxf(m, __shfl_xor(m, 8));
        float l = 0.f;
#pragma unroll
        for (int ni = 0; ni < 4; ++ni) {
          const float p = __expf(vals[ni] - m);
          l += p;
          P_lds[wave][row * 72 + ni * 16 + lr] = f2bf(p);
        }
        l += __shfl_xor(l, 1);
        l += __shfl_xor(l, 2);
        l += __shfl_xor(l, 4);
        l += __shfl_xor(l, 8);
        linv[mi][r] = 1.0f / l;       // rows>=49: 1/16, unused
      }
    }

    // ---- O = P @ V ----  A: P[m=mi*16+lr][k=kh*32+quad*8+j]
    //                      B: V[k][n=d] = VT[d=ni*16+lr][tok=kh*32+quad*8+j]
    f32x4 o[4][2] = {};
#pragma unroll
    for (int kh = 0; kh < 2; ++kh) {
      short8 vf[2];
#pragma unroll
      for (int ni = 0; ni < 2; ++ni)
        vf[ni] = *(const short8*)&VT[wave][(ni * 16 + lr) * 72 + kh * 32 + quad * 8];
#pragma unroll
      for (int mi = 0; mi < 4; ++mi) {
        short8 pf = *(const short8*)&P_lds[wave][(mi * 16 + lr) * 72 + kh * 32 + quad * 8];
#pragma unroll
        for (int ni = 0; ni < 2; ++ni)
          o[mi][ni] = __builtin_amdgcn_mfma_f32_16x16x32_bf16(pf, vf[ni], o[mi][ni], 0, 0, 0);
      }
    }

    // ---- epilogue: attnout[b][row][h*32+d] = O/l, bf16 ----
#pragma unroll
    for (int mi = 0; mi < 4; ++mi)
#pragma unroll
      for (int r = 0; r < 4; ++r) {
        const int row = mi * 16 + quad * 4 + r;
        if (row < 49) {
          const float li = linv[mi][r];
#pragma unroll
          for (int ni = 0; ni < 2; ++ni) {
            const int d = ni * 16 + lr;
            attnout[(base / 3) + (size_t)row * 384 + h * 32 + d] = f2bf(o[mi][ni][r] * li);
          }
        }
      }
  }
}

// ------------------------------------------------------------- launch -------
extern "C" void kernel_launch(void* const* d_in, const int* in_sizes, int n_in,
                              void* d_out, int out_size, void* d_ws, size_t ws_size,
                              hipStream_t stream) {
  const float* x      = (const float*)d_in[0];
  const float* mask   = (const float*)d_in[1];
  const float* qkv_w  = (const float*)d_in[2];
  const float* qkv_b  = (const float*)d_in[3];
  const float* proj_w = (const float*)d_in[4];
  const float* proj_b = (const float*)d_in[5];
  const float* rpb_t  = (const float*)d_in[6];
  float* out = (float*)d_out;

  // ws layout (all 16B aligned); attnout aliases xb (dead after gemm<0>).
  // total = 462,422,016 + 154,140,672 + 884,736 + 294,912 + 115,248 ≈ 618 MB
  char* ws = (char*)d_ws;
  u16* qkv    = (u16*)ws;                                    // [200704][1152] bf16
  u16* xb     = (u16*)(ws + 462422016u);                     // [200704][384] bf16
  u16* attnout = xb;                                         // alias (see above)
  u16* wqb    = (u16*)(ws + 462422016u + 154140672u);        // [1152][384] bf16
  u16* wpb    = wqb + 442368;                                // [384][384] bf16
  float* rpbf = (float*)((char*)wpb + 294912u);              // [12][49][49] f32

  prep_kernel<<<1096, 256, 0, stream>>>(x, qkv_w, proj_w, rpb_t, xb, wqb, wpb, rpbf);
  gemm_nt<0><<<dim3(9, 1568), 256, 0, stream>>>(xb, wqb, qkv_b, (void*)qkv, 1152);
  attn_kernel<<<4096, 256, 0, stream>>>(qkv, mask, rpbf, attnout);
  gemm_nt<1><<<dim3(3, 1568), 256, 0, stream>>>(attnout, wpb, proj_b, (void*)out, 384);
}

// Round 2
// 1185.441 us; speedup vs baseline: 1.1990x; 1.1990x over previous
//
#include <hip/hip_runtime.h>
#include <stdint.h>

// WindowAttention (Swin, 7x7, C=384, H=12, hd=32, B_=4096, nW=64), fp32 in/out.
// Strategy: bf16 MFMA for all three matmul stages (threshold 3.3e-2 allows it).
//   prep      : cast x / qkv_w / proj_w to bf16, expand rpb table to [12][49][49]
//   gemm_nt<0>: qkv = x @ qkv_w^T + b  (q-part scaled), bf16 out  [200704 x 1152]
//   attn      : wave-per-(window,head) attention (padded 49->64), bf16 out
//   gemm_nt<1>: out = attnout @ proj_w^T + b, fp32 out
// M=200704=1568*128, N=1152=9*128 / 384=3*128, K=384=12*32 -> no edge handling.

typedef unsigned short u16;
typedef short short8 __attribute__((ext_vector_type(8)));   // 8 x bf16 (4 VGPRs)
typedef float f32x4 __attribute__((ext_vector_type(4)));

static __device__ __forceinline__ u16 f2bf(float f) {
  unsigned u = __builtin_bit_cast(unsigned, f);
  return (u16)((u + 0x7fffu + ((u >> 16) & 1u)) >> 16);
}

// async global->LDS, 16B per lane. LDS dest = wave-uniform base + lane*16.
static __device__ __forceinline__ void async_cp16(const u16* g, u16* l) {
  __builtin_amdgcn_global_load_lds(
      (__attribute__((address_space(1))) unsigned int*)g,
      (__attribute__((address_space(3))) unsigned int*)l, 16, 0, 0);
}

// ---------------------------------------------------------------- prep ------
__global__ __launch_bounds__(256) void prep_kernel(
    const float* __restrict__ x, const float* __restrict__ wq,
    const float* __restrict__ wp, const float* __restrict__ rpt,
    u16* __restrict__ xb, u16* __restrict__ wqb, u16* __restrict__ wpb,
    float* __restrict__ rpbf)
{
  const int bid = blockIdx.x, tid = threadIdx.x;
  if (bid < 1024) {
    const float4* x4 = (const float4*)x;
    ushort4* o4 = (ushort4*)xb;
    for (unsigned i = bid * 256u + tid; i < 19267584u; i += 262144u) {
      float4 v = x4[i];
      ushort4 o; o.x = f2bf(v.x); o.y = f2bf(v.y); o.z = f2bf(v.z); o.w = f2bf(v.w);
      o4[i] = o;
    }
  } else if (bid < 1088) {
    for (unsigned i = (bid - 1024) * 256u + tid; i < 147456u; i += 16384u) {
      if (i < 110592u) {
        float4 v = ((const float4*)wq)[i];
        ushort4 o; o.x = f2bf(v.x); o.y = f2bf(v.y); o.z = f2bf(v.z); o.w = f2bf(v.w);
        ((ushort4*)wqb)[i] = o;
      } else {
        unsigned k = i - 110592u;
        float4 v = ((const float4*)wp)[k];
        ushort4 o; o.x = f2bf(v.x); o.y = f2bf(v.y); o.z = f2bf(v.z); o.w = f2bf(v.w);
        ((ushort4*)wpb)[k] = o;
      }
    }
  } else {
    for (int e = (bid - 1088) * 256 + tid; e < 28812; e += 2048) {
      int h = e / 2401, r2 = e - h * 2401;
      int i = r2 / 49, j = r2 - (r2 / 49) * 49;
      int rel = (i / 7 - j / 7 + 6) * 13 + (i % 7 - j % 7 + 6);
      rpbf[e] = rpt[rel * 12 + h];
    }
  }
}

// ------------------------------------------------------------- NT GEMM ------
// (unchanged from round 1 — m97-pattern; GEMM tuning deferred until its
//  dispatch rows are visible in the profile)
template <int MODE>
__global__ __launch_bounds__(256) void gemm_nt(
    const u16* __restrict__ A, const u16* __restrict__ Bw,
    const float* __restrict__ bias, void* __restrict__ Cp, int Ntot)
{
  __shared__ u16 As[128 * 32];
  __shared__ u16 Bs[128 * 32];
  const int tid = threadIdx.x;
  const int wave = tid >> 6, lane = tid & 63;
  const int lr = lane & 15, quad = lane >> 4;
  const int m0 = blockIdx.y * 128, n0 = blockIdx.x * 128;
  const int wm = (wave & 1) * 64, wn = (wave >> 1) * 64;

  const int e0 = tid * 8;
  const int row0 = e0 >> 5, col0 = e0 & 31;

  f32x4 acc[4][4] = {};
  for (int k0 = 0; k0 < 384; k0 += 32) {
    __syncthreads();
    async_cp16(&A[(size_t)(m0 + row0) * 384 + k0 + col0],      As + wave * 512);
    async_cp16(&A[(size_t)(m0 + 64 + row0) * 384 + k0 + col0], As + 2048 + wave * 512);
    async_cp16(&Bw[(size_t)(n0 + row0) * 384 + k0 + col0],      Bs + wave * 512);
    async_cp16(&Bw[(size_t)(n0 + 64 + row0) * 384 + k0 + col0], Bs + 2048 + wave * 512);
    __syncthreads();

    short8 af[4], bf[4];
#pragma unroll
    for (int mi = 0; mi < 4; ++mi)
      af[mi] = *(const short8*)&As[(wm + mi * 16 + lr) * 32 + quad * 8];
#pragma unroll
    for (int ni = 0; ni < 4; ++ni)
      bf[ni] = *(const short8*)&Bs[(wn + ni * 16 + lr) * 32 + quad * 8];
#pragma unroll
    for (int mi = 0; mi < 4; ++mi)
#pragma unroll
      for (int ni = 0; ni < 4; ++ni)
        acc[mi][ni] = __builtin_amdgcn_mfma_f32_16x16x32_bf16(af[mi], bf[ni], acc[mi][ni], 0, 0, 0);
  }

  float bv[4];
#pragma unroll
  for (int ni = 0; ni < 4; ++ni) bv[ni] = bias[n0 + wn + ni * 16 + lr];
#pragma unroll
  for (int mi = 0; mi < 4; ++mi)
#pragma unroll
    for (int ni = 0; ni < 4; ++ni) {
      const int gcol = n0 + wn + ni * 16 + lr;
#pragma unroll
      for (int r = 0; r < 4; ++r) {
        const size_t grow = (size_t)(m0 + wm + mi * 16 + quad * 4 + r);
        float v = acc[mi][ni][r] + bv[ni];
        if (MODE == 0) {
          if (gcol < 384) v *= 0.17677669529663687f;   // hd^-0.5 on q
          ((u16*)Cp)[grow * Ntot + gcol] = f2bf(v);
        } else {
          ((float*)Cp)[grow * Ntot + gcol] = v;
        }
      }
    }
}

// ------------------------------------------------------------ attention -----
// One WAVE per (window, head): grid 12288 x 256, wave w of block bl handles
// window b = bl/3, head h = (bl%3)*4 + w. No __syncthreads, no head loop.
// QK^T operands straight from global in fragment layout (hd=32 = one K-step).
// rpb + mask added from global (L2/L3-resident, coalesced across lr).
// P and V^T live in per-wave LDS with XOR-swizzled 16B chunks:
//   addr(row, col) = row*64 + ((col>>3 ^ (row&7))*8) + (col&7)   [u16 units]
// -> b128 fragment reads are bank-conflict-free. 12.3KB/wave, 49.2KB/block
// -> 3 blocks/CU (12 waves), matching the ~148-VGPR cap.
__global__ __launch_bounds__(256) void attn_kernel(
    const u16* __restrict__ qkv, const float* __restrict__ mask,
    const float* __restrict__ rpbf, u16* __restrict__ attnout)
{
  __shared__ u16 P_lds[4][64 * 64];
  __shared__ u16 VT_lds[4][32 * 64];
  const int tid = threadIdx.x;
  const int wave = tid >> 6, lane = tid & 63;
  const int lr = lane & 15, quad = lane >> 4;
  const int b = blockIdx.x / 3;
  const int h = (blockIdx.x - b * 3) * 4 + wave;

  const size_t base = (size_t)b * (49 * 1152);
  u16* P  = P_lds[wave];
  u16* Vt = VT_lds[wave];
  const short8 z8 = {0, 0, 0, 0, 0, 0, 0, 0};

  // ---- stage V^T (vectorized 16B loads, swizzled scatter; pad toks zeroed
  //      so LDS garbage (possibly NaN-pattern) never reaches the MFMA) ----
  {
    const int dh = lane & 3;          // 8-d group: d = dh*8 + j
    const int tk0 = lane >> 2;        // tok within pass
#pragma unroll
    for (int p = 0; p < 4; ++p) {
      const int tok = p * 16 + tk0;
      short8 v = z8;
      if (tok < 49)
        v = *(const short8*)&qkv[base + (size_t)tok * 1152 + 768 + h * 32 + dh * 8];
#pragma unroll
      for (int j = 0; j < 8; ++j) {
        const int d = dh * 8 + j;     // d&7 == j
        Vt[d * 64 + (((tok >> 3) ^ j) * 8) + (tok & 7)] = ((const u16*)&v)[j];
      }
    }
  }

  // ---- QK^T ----  A: Q[m=mi*16+lr][k=quad*8+j]   B: K[n=ni*16+lr][k=...]
  short8 qf[4], kf[4];
#pragma unroll
  for (int mi = 0; mi < 4; ++mi) {
    const int row = mi * 16 + lr;
    qf[mi] = (row < 49)
        ? *(const short8*)&qkv[base + (size_t)row * 1152 + h * 32 + quad * 8] : z8;
  }
#pragma unroll
  for (int ni = 0; ni < 4; ++ni) {
    const int tok = ni * 16 + lr;
    kf[ni] = (tok < 49)
        ? *(const short8*)&qkv[base + (size_t)tok * 1152 + 384 + h * 32 + quad * 8] : z8;
  }
  f32x4 s[4][4] = {};
#pragma unroll
  for (int mi = 0; mi < 4; ++mi)
#pragma unroll
    for (int ni = 0; ni < 4; ++ni)
      s[mi][ni] = __builtin_amdgcn_mfma_f32_16x16x32_bf16(qf[mi], kf[ni], s[mi][ni], 0, 0, 0);

  // ---- bias + mask + softmax (quad-local rows), P -> LDS bf16 (swizzled) ----
  const float* rh = &rpbf[h * 2401];
  const float* mw = &mask[(size_t)(b & 63) * 2401];
  float linv[4][4];
#pragma unroll
  for (int mi = 0; mi < 4; ++mi) {
#pragma unroll
    for (int r = 0; r < 4; ++r) {
      const int row = mi * 16 + quad * 4 + r;
      float vals[4];
#pragma unroll
      for (int ni = 0; ni < 4; ++ni) {
        const int col = ni * 16 + lr;
        float v;
        if (row < 49 && col < 49)
          v = s[mi][ni][r] + rh[row * 49 + col] + mw[row * 49 + col];
        else
          v = -1e30f;                 // finite: pad rows -> exp(0), never output
        vals[ni] = v;
      }
      float m = fmaxf(fmaxf(vals[0], vals[1]), fmaxf(vals[2], vals[3]));
      m = fmaxf(m, __shfl_xor(m, 1));
      m = fmaxf(m, __shfl_xor(m, 2));
      m = fmaxf(m, __shfl_xor(m, 4));
      m = fmaxf(m, __shfl_xor(m, 8));
      float l = 0.f;
#pragma unroll
      for (int ni = 0; ni < 4; ++ni) {
        const float p = __expf(vals[ni] - m);
        l += p;
        const int col = ni * 16 + lr;
        P[row * 64 + (((col >> 3) ^ (row & 7)) * 8) + (col & 7)] = f2bf(p);
      }
      l += __shfl_xor(l, 1);
      l += __shfl_xor(l, 2);
      l += __shfl_xor(l, 4);
      l += __shfl_xor(l, 8);
      linv[mi][r] = 1.0f / l;
    }
  }

  // ---- O = P @ V ----  A: P[m=mi*16+lr][k=kh*32+quad*8+j]
  //                      B: VT[n=d=ni*16+lr][k=tok=kh*32+quad*8+j]
  f32x4 o[4][2] = {};
#pragma unroll
  for (int kh = 0; kh < 2; ++kh) {
    const int chunk = (kh * 4 + quad) ^ (lr & 7);   // row&7 == lr&7 for both
    short8 vf[2];
#pragma unroll
    for (int ni = 0; ni < 2; ++ni)
      vf[ni] = *(const short8*)&Vt[(ni * 16 + lr) * 64 + chunk * 8];
#pragma unroll
    for (int mi = 0; mi < 4; ++mi) {
      short8 pf = *(const short8*)&P[(mi * 16 + lr) * 64 + chunk * 8];
#pragma unroll
      for (int ni = 0; ni < 2; ++ni)
        o[mi][ni] = __builtin_amdgcn_mfma_f32_16x16x32_bf16(pf, vf[ni], o[mi][ni], 0, 0, 0);
    }
  }

  // ---- epilogue: attnout[b][row][h*32+d] = O/l, bf16 ----
  u16* outp = attnout + (size_t)b * (49 * 384) + h * 32;
#pragma unroll
  for (int mi = 0; mi < 4; ++mi)
#pragma unroll
    for (int r = 0; r < 4; ++r) {
      const int row = mi * 16 + quad * 4 + r;
      if (row < 49) {
        const float li = linv[mi][r];
#pragma unroll
        for (int ni = 0; ni < 2; ++ni)
          outp[row * 384 + ni * 16 + lr] = f2bf(o[mi][ni][r] * li);
      }
    }
}

// ------------------------------------------------------------- launch -------
extern "C" void kernel_launch(void* const* d_in, const int* in_sizes, int n_in,
                              void* d_out, int out_size, void* d_ws, size_t ws_size,
                              hipStream_t stream) {
  const float* x      = (const float*)d_in[0];
  const float* mask   = (const float*)d_in[1];
  const float* qkv_w  = (const float*)d_in[2];
  const float* qkv_b  = (const float*)d_in[3];
  const float* proj_w = (const float*)d_in[4];
  const float* proj_b = (const float*)d_in[5];
  const float* rpb_t  = (const float*)d_in[6];
  float* out = (float*)d_out;

  // ws layout identical to round 1 (618 MB, proven to fit).
  char* ws = (char*)d_ws;
  u16* qkv    = (u16*)ws;                                    // [200704][1152] bf16
  u16* xb     = (u16*)(ws + 462422016u);                     // [200704][384] bf16
  u16* attnout = xb;                                         // alias (xb dead)
  u16* wqb    = (u16*)(ws + 462422016u + 154140672u);        // [1152][384] bf16
  u16* wpb    = wqb + 442368;                                // [384][384] bf16
  float* rpbf = (float*)((char*)wpb + 294912u);              // [12][49][49] f32

  prep_kernel<<<1096, 256, 0, stream>>>(x, qkv_w, proj_w, rpb_t, xb, wqb, wpb, rpbf);
  gemm_nt<0><<<dim3(9, 1568), 256, 0, stream>>>(xb, wqb, qkv_b, (void*)qkv, 1152);
  attn_kernel<<<12288, 256, 0, stream>>>(qkv, mask, rpbf, attnout);
  gemm_nt<1><<<dim3(3, 1568), 256, 0, stream>>>(attnout, wpb, proj_b, (void*)out, 384);
}